// Round 1
// baseline (27446.286 us; speedup 1.0000x reference)
//
#include <hip/hip_runtime.h>

// ---- problem constants ----
#define T_SEQ 1000
#define NS 128
#define NE 4
#define DIN 132
#define G3 768
#define WGS 512
#define NWG_GRP 4

typedef __attribute__((ext_vector_type(8))) short short8;
typedef __attribute__((ext_vector_type(4))) float floatx4;

// ---- workspace layout (bytes) ----
#define CNT_OFF 0
#define CNT_SZ (32*(T_SEQ+1)*4)          // 128128
#define HX_OFF 131072
#define HX_SZ  (32*2*4096*4)             // 1 MiB   (per group,slot: 16 rows x 256 f32)
#define XS_OFF (HX_OFF + HX_SZ)          // xstage: per group,slot: 5x64x8 bf16 = 2560 u16

#define MFMA16(a,b,c) __builtin_amdgcn_mfma_f32_16x16x32_bf16((a),(b),(c),0,0,0)

__device__ __forceinline__ unsigned short f2bf(float f){
  unsigned u = __float_as_uint(f);
  return (unsigned short)((u + 0x7FFFu + ((u>>16)&1u)) >> 16);   // RNE
}
__device__ __forceinline__ float bf2f(unsigned short b){
  return __uint_as_float(((unsigned)b)<<16);
}
__device__ __forceinline__ unsigned long long ld64a(const void* p){
  return __hip_atomic_load((const unsigned long long*)p, __ATOMIC_RELAXED, __HIP_MEMORY_SCOPE_AGENT);
}
__device__ __forceinline__ void st32a(void* p, unsigned v){
  __hip_atomic_store((unsigned*)p, v, __ATOMIC_RELAXED, __HIP_MEMORY_SCOPE_AGENT);
}

__global__ __launch_bounds__(WGS, 2) void bigru_persist(
  const float* __restrict__ spike, const float* __restrict__ extin,
  const int* __restrict__ lens,
  const float* __restrict__ WiF, const float* __restrict__ WhF,
  const float* __restrict__ biF, const float* __restrict__ bhF,
  const float* __restrict__ WiB, const float* __restrict__ WhB,
  const float* __restrict__ biB, const float* __restrict__ bhB,
  float* __restrict__ out,
  unsigned* __restrict__ cnt, float* __restrict__ hx, unsigned short* __restrict__ xs)
{
  const int tid = threadIdx.x;
  const int bid = blockIdx.x;
  const int g   = bid >> 2;          // group 0..31 (16 fwd, 16 bwd)
  const int s   = bid & 3;           // column-slice 0..3 (64 h-dims each)
  const int dir = g >> 4;
  const int b_base = (g & 15) << 4;  // 16 examples per group
  const int w  = tid >> 6;           // wave 0..7
  const int l  = tid & 63;
  const int dg = w >> 1;             // dim-group 0..3 (16 dims)
  const int ks = w & 1;              // K-half
  const int col = l & 15;
  const int q   = l >> 4;
  const int jd  = s*64 + dg*16 + col;   // global h-dim 0..255

  const float* Wi  = dir ? WiB : WiF;
  const float* Wh  = dir ? WhB : WhF;
  const float* bi  = dir ? biB : biF;
  const float* bhn = dir ? bhB : bhF;

  __shared__ __align__(16) char  ldsA[13*64*16];      // A fragments (8 h-kg + 5 x-kg)
  __shared__ __align__(16) float ldsC[4][4][16][20];  // K-split partials, padded
  __shared__ int ldsL[16];

  unsigned*       cg  = cnt + g*(T_SEQ+1);
  float*          hxg = hx + (size_t)g*2*4096;
  unsigned short* xsg = xs + (size_t)g*2*2560;

  if (tid < 16) ldsL[tid] = lens[b_base + tid];
  __syncthreads();

  // ---- persistent B fragments (W = W_hi + W_lo, both bf16) ----
  const int q8 = q*8;
  short8 Bh[4][3][2];   // [h-kg][gate][hi/lo]
  short8 Bx[3][3][2];   // [x-kg][gate][hi/lo]
  #pragma unroll
  for (int hk=0; hk<4; ++hk){
    const int k0 = (ks*4+hk)*32 + q8;
    #pragma unroll
    for (int gt=0; gt<3; ++gt){
      const int c = gt*256 + jd;
      #pragma unroll
      for (int i=0;i<8;++i){
        float wv = Wh[(size_t)(k0+i)*G3 + c];
        unsigned short hb = f2bf(wv);
        Bh[hk][gt][0][i] = (short)hb;
        Bh[hk][gt][1][i] = (short)f2bf(wv - bf2f(hb));
      }
    }
  }
  #pragma unroll
  for (int xk=0; xk<3; ++xk){
    const bool xv = (ks==0) || (xk<2);
    const int kxg = (ks==0) ? xk : (3+xk);
    const int k0 = kxg*32 + q8;
    #pragma unroll
    for (int gt=0; gt<3; ++gt){
      const int c = gt*256 + jd;
      #pragma unroll
      for (int i=0;i<8;++i){
        float wv = (xv && (k0+i) < DIN) ? Wi[(size_t)(k0+i)*G3 + c] : 0.f;
        unsigned short hb = f2bf(wv);
        Bx[xk][gt][0][i] = (short)hb;
        Bx[xk][gt][1][i] = (short)f2bf(wv - bf2f(hb));
      }
    }
  }

  const float bir = bi[jd], biz = bi[256+jd], bin = bi[512+jd], bhv = bhn[jd];
  int   Lr[4];
  float hold[4];
  #pragma unroll
  for (int j=0;j<4;++j){ Lr[j] = ldsL[q*4+j]; hold[j] = 0.f; }

  // stage x (bf16, frag layout) for step tt into global xstage; this WG's duty rows
  auto stage_x = [&](int tt, int base, int stride){
    const int slot = tt & 1;
    for (int m = base; m < 320; m += stride){
      const int lr = m / 80;
      const int p  = m - lr*80;
      const int kx = p*2;
      const int row = s*4 + lr;
      const int b   = b_base + row;
      const int Lx  = ldsL[row];
      int tp = dir ? (Lx-1-tt) : tt;
      if (tp < 0) tp += T_SEQ;
      const size_t xb = (size_t)b*T_SEQ + tp;
      float v0 = (kx  <NS) ? spike[xb*NS + kx  ] : ((kx  <DIN) ? extin[xb*NE + (kx  -NS)] : 0.f);
      float v1 = (kx+1<NS) ? spike[xb*NS + kx+1] : ((kx+1<DIN) ? extin[xb*NE + (kx+1-NS)] : 0.f);
      const unsigned val = (unsigned)f2bf(v0) | (((unsigned)f2bf(v1))<<16);
      const int kgx = kx>>5, sub=(kx>>3)&3, ii = kx&7;
      st32a(xsg + slot*2560 + ((kgx*64 + (row + 16*sub))*8 + ii), val);
    }
  };

  // prologue: stage x for t=0, then signal
  stage_x(0, tid, WGS);
  __threadfence();
  __syncthreads();
  if (tid==0) __hip_atomic_fetch_add(&cg[0], 1u, __ATOMIC_RELEASE, __HIP_MEMORY_SCOPE_AGENT);

  for (int t=0; t<T_SEQ; ++t){
    // 1. wait for group: h(t-1) and x(t) ready
    if (tid==0){
      while (__hip_atomic_load(&cg[t], __ATOMIC_ACQUIRE, __HIP_MEMORY_SCOPE_AGENT) < (unsigned)NWG_GRP)
        __builtin_amdgcn_s_sleep(1);
    }
    __syncthreads();

    // 2. stage A fragments into LDS
    {
      // h fragment (one per thread): frag f = tid = kg*64+lane
      const int kg = tid >> 6, lane = tid & 63;
      const int row = lane & 15;
      const int k0  = kg*32 + (lane>>4)*8;
      short8 v;
      if (t == 0){
        #pragma unroll
        for (int i=0;i<8;++i) v[i] = 0;
      } else {
        const float* src = hxg + ((t&1)^1)*4096 + row*256 + k0;
        unsigned long long a0 = ld64a(src), a1 = ld64a(src+2), a2 = ld64a(src+4), a3 = ld64a(src+6);
        float f0=__uint_as_float((unsigned)a0), f1=__uint_as_float((unsigned)(a0>>32));
        float f2=__uint_as_float((unsigned)a1), f3=__uint_as_float((unsigned)(a1>>32));
        float f4=__uint_as_float((unsigned)a2), f5=__uint_as_float((unsigned)(a2>>32));
        float f6=__uint_as_float((unsigned)a3), f7=__uint_as_float((unsigned)(a3>>32));
        v[0]=(short)f2bf(f0); v[1]=(short)f2bf(f1); v[2]=(short)f2bf(f2); v[3]=(short)f2bf(f3);
        v[4]=(short)f2bf(f4); v[5]=(short)f2bf(f5); v[6]=(short)f2bf(f6); v[7]=(short)f2bf(f7);
      }
      *(short8*)(ldsA + tid*16) = v;
      // x fragment (already bf16 frag layout in global): frags 512..831
      if (tid < 320){
        const unsigned long long* src = (const unsigned long long*)(xsg + (t&1)*2560) + tid*2;
        union { unsigned long long qq[2]; short8 s8; } u;
        u.qq[0] = ld64a(src); u.qq[1] = ld64a(src+1);
        *(short8*)(ldsA + (512+tid)*16) = u.s8;
      }
    }
    __syncthreads();

    // 3. MFMA: 4 accumulators, hi+lo compensated weights
    floatx4 aR={0.f,0.f,0.f,0.f}, aZ={0.f,0.f,0.f,0.f}, aNH={0.f,0.f,0.f,0.f}, aNX={0.f,0.f,0.f,0.f};
    #pragma unroll
    for (int hk=0; hk<4; ++hk){
      const int kg = ks*4 + hk;
      const short8 a = *(const short8*)(ldsA + (kg*64 + l)*16);
      aR  = MFMA16(a, Bh[hk][0][0], aR ); aZ  = MFMA16(a, Bh[hk][1][0], aZ ); aNH = MFMA16(a, Bh[hk][2][0], aNH);
      aR  = MFMA16(a, Bh[hk][0][1], aR ); aZ  = MFMA16(a, Bh[hk][1][1], aZ ); aNH = MFMA16(a, Bh[hk][2][1], aNH);
    }
    #pragma unroll
    for (int xk=0; xk<3; ++xk){
      if (ks==0 || xk<2){
        const int kgx = (ks==0) ? xk : (3+xk);
        const short8 a = *(const short8*)(ldsA + ((8+kgx)*64 + l)*16);
        aR  = MFMA16(a, Bx[xk][0][0], aR ); aZ  = MFMA16(a, Bx[xk][1][0], aZ ); aNX = MFMA16(a, Bx[xk][2][0], aNX);
        aR  = MFMA16(a, Bx[xk][0][1], aR ); aZ  = MFMA16(a, Bx[xk][1][1], aZ ); aNX = MFMA16(a, Bx[xk][2][1], aNX);
      }
    }

    if (ks==0){
      *(floatx4*)&ldsC[dg][0][col][q*4] = aR;
      *(floatx4*)&ldsC[dg][1][col][q*4] = aZ;
      *(floatx4*)&ldsC[dg][2][col][q*4] = aNH;
      *(floatx4*)&ldsC[dg][3][col][q*4] = aNX;
    }
    __syncthreads();

    // 4. epilogue (odd waves) / x-prefetch duty (even waves)
    if (ks==1){
      aR  += *(const floatx4*)&ldsC[dg][0][col][q*4];
      aZ  += *(const floatx4*)&ldsC[dg][1][col][q*4];
      aNH += *(const floatx4*)&ldsC[dg][2][col][q*4];
      aNX += *(const floatx4*)&ldsC[dg][3][col][q*4];
      float* hdst = hxg + (t&1)*4096;
      #pragma unroll
      for (int j=0;j<4;++j){
        const int row = q*4 + j;
        const float gr = aR[j] + bir;
        const float gz = aZ[j] + biz;
        const float r = __fdividef(1.f, 1.f + __expf(-gr));
        const float z = __fdividef(1.f, 1.f + __expf(-gz));
        float pn = aNX[j] + bin + r*(aNH[j] + bhv);
        pn = fminf(fmaxf(pn, -20.f), 20.f);
        const float e2 = __expf(-2.f*pn);
        const float n  = __fdividef(1.f - e2, 1.f + e2);
        const float hn  = (1.f - z)*n + z*hold[j];
        const float hnx = (t < Lr[j]) ? hn : hold[j];   // mask: keep state on padding
        hold[j] = hnx;
        int tp = dir ? (Lr[j]-1-t) : t;
        if (tp < 0) tp += T_SEQ;
        out[((size_t)(b_base+row)*T_SEQ + tp)*512 + dir*256 + jd] = hn;  // new_h always
        st32a(hdst + row*256 + jd, __float_as_uint(hnx));
      }
    } else if (t < T_SEQ-1){
      stage_x(t+1, dg*64 + l, 256);
    }

    __threadfence();
    __syncthreads();
    if (tid==0) __hip_atomic_fetch_add(&cg[t+1], 1u, __ATOMIC_RELEASE, __HIP_MEMORY_SCOPE_AGENT);
  }
}

extern "C" void kernel_launch(void* const* d_in, const int* in_sizes, int n_in,
                              void* d_out, int out_size, void* d_ws, size_t ws_size,
                              hipStream_t stream) {
  (void)in_sizes; (void)n_in; (void)out_size; (void)ws_size;
  const float* spike = (const float*)d_in[0];
  const float* extin = (const float*)d_in[1];
  const int*   lens  = (const int*)  d_in[2];
  const float* WiF   = (const float*)d_in[3];
  const float* WhF   = (const float*)d_in[4];
  const float* biF   = (const float*)d_in[5];
  const float* bhF   = (const float*)d_in[6];
  const float* WiB   = (const float*)d_in[7];
  const float* WhB   = (const float*)d_in[8];
  const float* biB   = (const float*)d_in[9];
  const float* bhB   = (const float*)d_in[10];
  float* out = (float*)d_out;
  char* ws = (char*)d_ws;
  unsigned*       cnt = (unsigned*)      (ws + CNT_OFF);
  float*          hx  = (float*)         (ws + HX_OFF);
  unsigned short* xs  = (unsigned short*)(ws + XS_OFF);

  hipMemsetAsync(cnt, 0, CNT_SZ, stream);
  bigru_persist<<<dim3(128), dim3(WGS), 0, stream>>>(
      spike, extin, lens, WiF, WhF, biF, bhF, WiB, WhB, biB, bhB, out, cnt, hx, xs);
}

// Round 2
// 4424.793 us; speedup vs baseline: 6.2028x; 6.2028x over previous
//
#include <hip/hip_runtime.h>

// ---- problem constants ----
#define T_SEQ 1000
#define NS 128
#define NE 4
#define DIN 132
#define G3 768
#define WGS 512

typedef __attribute__((ext_vector_type(8))) short short8;
typedef __attribute__((ext_vector_type(4))) float floatx4;

// ---- workspace layout (bytes) ----
#define CNT_OFF 0
#define HX_OFF  131072
#define HX_BYTES (32*2*8192)             // per group: 2 slots x 8 frags x 64 lanes x 16B
#define WS_ZERO_BYTES (HX_OFF + HX_BYTES)

#define MFMA16(a,b,c) __builtin_amdgcn_mfma_f32_16x16x32_bf16((a),(b),(c),0,0,0)

__device__ __forceinline__ unsigned short f2bf(float f){
  unsigned u = __float_as_uint(f);
  return (unsigned short)((u + 0x7FFFu + ((u>>16)&1u)) >> 16);   // RNE
}
__device__ __forceinline__ float bf2f(unsigned short b){
  return __uint_as_float(((unsigned)b)<<16);
}
__device__ __forceinline__ unsigned long long ld64a(const void* p){
  return __hip_atomic_load((const unsigned long long*)p, __ATOMIC_RELAXED, __HIP_MEMORY_SCOPE_AGENT);
}
__device__ __forceinline__ void st64a(void* p, unsigned long long v){
  __hip_atomic_store((unsigned long long*)p, v, __ATOMIC_RELAXED, __HIP_MEMORY_SCOPE_AGENT);
}

__global__ __launch_bounds__(WGS, 2) void bigru2(
  const float* __restrict__ spike, const float* __restrict__ extin,
  const int* __restrict__ lens,
  const float* __restrict__ WiF, const float* __restrict__ WhF,
  const float* __restrict__ biF, const float* __restrict__ bhF,
  const float* __restrict__ WiB, const float* __restrict__ WhB,
  const float* __restrict__ biB, const float* __restrict__ bhB,
  float* __restrict__ out,
  unsigned* __restrict__ cnt, char* __restrict__ hx)
{
  const int tid = threadIdx.x;
  const int bid = blockIdx.x;
  const int g   = bid >> 2;          // group 0..31 (16 fwd, 16 bwd)
  const int s   = bid & 3;           // column-slice 0..3 (64 h-dims each)
  const int dir = g >> 4;
  const int b_base = (g & 15) << 4;  // 16 examples per group
  const int w  = tid >> 6;           // wave 0..7
  const int l  = tid & 63;
  const int dg = w >> 1;             // dim-group 0..3 (16 dims)
  const int ks = w & 1;              // K-half
  const int col = l & 15;
  const int q   = l >> 4;
  const int jd  = s*64 + dg*16 + col;   // global h-dim 0..255

  const float* Wi  = dir ? WiB : WiF;
  const float* Wh  = dir ? WhB : WhF;
  const float* bi  = dir ? biB : biF;
  const float* bhn = dir ? bhB : bhF;

  __shared__ __align__(16) char  ldsA[8*64*16];      // h A-frags (bf16)
  __shared__ __align__(16) char  ldsX[5*64*16];      // x A-frags (bf16), pad region stays 0
  __shared__ __align__(16) float ldsC[4][4][16][20]; // K-split partials, padded
  __shared__ __align__(16) char  ldsHT[16*128];      // h bf16 transpose (XOR-swizzled)
  __shared__ int ldsL[16];

  unsigned* cg  = cnt + g*T_SEQ;          // cnt[t] = #WGs done with step t
  char*     hxg = hx + (size_t)g*2*8192;

  if (tid < 16) ldsL[tid] = lens[b_base + tid];
  if (tid < 320) *(floatx4*)(ldsX + tid*16) = floatx4{0.f,0.f,0.f,0.f};
  __syncthreads();

  // ---- persistent B fragments (W = W_hi + W_lo, both bf16) ----
  const int q8 = q*8;
  short8 Bh[4][3][2];   // [h-kg][gate][hi/lo]
  short8 Bx[3][3][2];   // [x-kg][gate][hi/lo]
  #pragma unroll
  for (int hk=0; hk<4; ++hk){
    const int k0 = (ks*4+hk)*32 + q8;
    #pragma unroll
    for (int gt=0; gt<3; ++gt){
      const int c = gt*256 + jd;
      #pragma unroll
      for (int i=0;i<8;++i){
        float wv = Wh[(size_t)(k0+i)*G3 + c];
        unsigned short hb = f2bf(wv);
        Bh[hk][gt][0][i] = (short)hb;
        Bh[hk][gt][1][i] = (short)f2bf(wv - bf2f(hb));
      }
    }
  }
  #pragma unroll
  for (int xk=0; xk<3; ++xk){
    const bool xv = (ks==0) || (xk<2);
    const int kxg = (ks==0) ? xk : (3+xk);
    const int k0 = kxg*32 + q8;
    #pragma unroll
    for (int gt=0; gt<3; ++gt){
      const int c = gt*256 + jd;
      #pragma unroll
      for (int i=0;i<8;++i){
        float wv = (xv && (k0+i) < DIN) ? Wi[(size_t)(k0+i)*G3 + c] : 0.f;
        unsigned short hb = f2bf(wv);
        Bx[xk][gt][0][i] = (short)hb;
        Bx[xk][gt][1][i] = (short)f2bf(wv - bf2f(hb));
      }
    }
  }

  const float bir = bi[jd], biz = bi[256+jd], bin = bi[512+jd], bhv = bhn[jd];
  int   Lr[4];
  float hold[4];
  #pragma unroll
  for (int j=0;j<4;++j){ Lr[j] = ldsL[q*4+j]; hold[j] = 0.f; }

  // x staging helpers: thread handles pack m (row = m/33, k0 = (m%33)*4)
  auto xload = [&](int m, int tt)->float4{
    const int row = m/33, pk = m - row*33, k0 = pk*4;
    const int L = ldsL[row];
    int tp = dir ? (L-1-tt) : tt;
    if (tp < 0) tp += T_SEQ;
    const size_t xb = (size_t)(b_base+row)*T_SEQ + tp;
    if (k0 < NS) return *(const float4*)(spike + xb*NS + k0);
    return *(const float4*)(extin + xb*NE);        // k0 == 128 -> 4 external dims
  };
  auto xstore = [&](int m, float4 v){
    const int row = m/33, pk = m - row*33, k0 = pk*4;
    const int kg = k0>>5, sub = (k0>>3)&3, ii = k0&7;
    const int off = ((kg*64 + row + 16*sub)*8 + ii)*2;
    unsigned lo = (unsigned)f2bf(v.x) | (((unsigned)f2bf(v.y))<<16);
    unsigned hi = (unsigned)f2bf(v.z) | (((unsigned)f2bf(v.w))<<16);
    *(unsigned*)(ldsX + off)     = lo;
    *(unsigned*)(ldsX + off + 4) = hi;
  };

  // prologue: stage x(0)  (every tid has pack tid; tid<16 also pack tid+512)
  {
    float4 a = xload(tid, 0);  xstore(tid, a);
    if (tid < 16){ float4 b = xload(tid+512, 0); xstore(tid+512, b); }
  }

  for (int t=0; t<T_SEQ; ++t){
    __syncthreads();   // sync_a : ldsX(t), ldsHT free, ldsA free

    // drain previous step's frag exports, then publish completion (wave0 only;
    // overlaps other waves' staging + x-MFMA work)
    if (w==0 && t>0){
      asm volatile("s_waitcnt vmcnt(0)" ::: "memory");
      if (l==0) __hip_atomic_fetch_add(&cg[t-1], 1u, __ATOMIC_RELAXED, __HIP_MEMORY_SCOPE_AGENT);
    }

    // issue x(t+1) global loads early (T14: write to LDS after sync_b)
    float4 sxa, sxb;
    if (t < T_SEQ-1){
      sxa = xload(tid, t+1);
      if (tid < 16) sxb = xload(tid+512, t+1);
    }

    // x-part MFMAs (h-independent) while the h exchange completes
    floatx4 aR={0.f,0.f,0.f,0.f}, aZ={0.f,0.f,0.f,0.f}, aNH={0.f,0.f,0.f,0.f}, aNX={0.f,0.f,0.f,0.f};
    if (ks==0){
      #pragma unroll
      for (int xk=0; xk<3; ++xk){
        const short8 a = *(const short8*)(ldsX + (xk*64 + l)*16);
        aR  = MFMA16(a, Bx[xk][0][0], aR ); aZ  = MFMA16(a, Bx[xk][1][0], aZ ); aNX = MFMA16(a, Bx[xk][2][0], aNX);
        aR  = MFMA16(a, Bx[xk][0][1], aR ); aZ  = MFMA16(a, Bx[xk][1][1], aZ ); aNX = MFMA16(a, Bx[xk][2][1], aNX);
      }
    } else {
      #pragma unroll
      for (int xk=0; xk<2; ++xk){
        const short8 a = *(const short8*)(ldsX + ((3+xk)*64 + l)*16);
        aR  = MFMA16(a, Bx[xk][0][0], aR ); aZ  = MFMA16(a, Bx[xk][1][0], aZ ); aNX = MFMA16(a, Bx[xk][2][0], aNX);
        aR  = MFMA16(a, Bx[xk][0][1], aR ); aZ  = MFMA16(a, Bx[xk][1][1], aZ ); aNX = MFMA16(a, Bx[xk][2][1], aNX);
      }
    }

    // wait for all 4 WGs to have published h(t-1)
    if (t > 0 && tid == 0){
      while (__hip_atomic_load(&cg[t-1], __ATOMIC_RELAXED, __HIP_MEMORY_SCOPE_AGENT) < 4u)
        __builtin_amdgcn_s_sleep(1);
    }
    __syncthreads();   // sync_b
    __builtin_amdgcn_sched_barrier(0);

    // fetch h(t-1) bf16 A-frags (pre-transposed by producers) into LDS: 512 x 16B
    {
      const char* src = hxg + (((t&1)^1)*8192) + tid*16;
      unsigned long long a0 = ld64a(src), a1 = ld64a(src+8);
      union { unsigned long long qq[2]; short8 v; } u;
      u.qq[0] = a0; u.qq[1] = a1;
      *(short8*)(ldsA + tid*16) = u.v;
    }
    // x(t+1): convert + LDS write (reads of x(t) all happened before sync_b)
    if (t < T_SEQ-1){
      xstore(tid, sxa);
      if (tid < 16) xstore(tid+512, sxb);
    }
    __syncthreads();   // sync_c

    // h-part MFMAs
    #pragma unroll
    for (int hk=0; hk<4; ++hk){
      const int kg = ks*4 + hk;
      const short8 a = *(const short8*)(ldsA + (kg*64 + l)*16);
      aR  = MFMA16(a, Bh[hk][0][0], aR ); aZ  = MFMA16(a, Bh[hk][1][0], aZ ); aNH = MFMA16(a, Bh[hk][2][0], aNH);
      aR  = MFMA16(a, Bh[hk][0][1], aR ); aZ  = MFMA16(a, Bh[hk][1][1], aZ ); aNH = MFMA16(a, Bh[hk][2][1], aNH);
    }

    if (ks==0){
      *(floatx4*)&ldsC[dg][0][col][q*4] = aR;
      *(floatx4*)&ldsC[dg][1][col][q*4] = aZ;
      *(floatx4*)&ldsC[dg][2][col][q*4] = aNH;
      *(floatx4*)&ldsC[dg][3][col][q*4] = aNX;
    }
    __syncthreads();   // sync_d

    if (ks==1){
      aR  += *(const floatx4*)&ldsC[dg][0][col][q*4];
      aZ  += *(const floatx4*)&ldsC[dg][1][col][q*4];
      aNH += *(const floatx4*)&ldsC[dg][2][col][q*4];
      aNX += *(const floatx4*)&ldsC[dg][3][col][q*4];
      #pragma unroll
      for (int j=0;j<4;++j){
        const int rj = q*4 + j;
        const float gr = aR[j] + bir;
        const float gz = aZ[j] + biz;
        const float r = __fdividef(1.f, 1.f + __expf(-gr));
        const float z = __fdividef(1.f, 1.f + __expf(-gz));
        float pn = aNX[j] + bin + r*(aNH[j] + bhv);
        pn = fminf(fmaxf(pn, -20.f), 20.f);
        const float e2 = __expf(-2.f*pn);
        const float n  = __fdividef(1.f - e2, 1.f + e2);
        const float hn  = (1.f - z)*n + z*hold[j];
        const float hnx = (t < Lr[j]) ? hn : hold[j];   // keep state on padding
        hold[j] = hnx;
        int tp = dir ? (Lr[j]-1-t) : t;
        if (tp < 0) tp += T_SEQ;
        out[((size_t)(b_base+rj)*T_SEQ + tp)*512 + dir*256 + jd] = hn;  // new_h always
        // transpose-store h into LDS (bf16, XOR-swizzled for 16B export reads)
        const int off = rj*128 + ((((dg*16+col)*2)) ^ ((rj&7)<<4));
        *(unsigned short*)(ldsHT + off) = f2bf(hnx);
      }
    }
    __syncthreads();   // sync_e

    // wave0 exports this slice's two A-frags (kg = 2s, 2s+1) to LLC
    if (w==0 && t < T_SEQ-1){
      #pragma unroll
      for (int kgl=0; kgl<2; ++kgl){
        const int r = l & 15;
        const int off = r*128 + (((kgl*32 + (l>>4)*8)*2) ^ ((r&7)<<4));
        union { short8 v; unsigned long long qq[2]; } u;
        u.v = *(const short8*)(ldsHT + off);
        char* dst = hxg + (t&1)*8192 + (((s*2+kgl)*64 + l)*16);
        st64a(dst,   u.qq[0]);
        st64a(dst+8, u.qq[1]);
      }
    }
  }
}

extern "C" void kernel_launch(void* const* d_in, const int* in_sizes, int n_in,
                              void* d_out, int out_size, void* d_ws, size_t ws_size,
                              hipStream_t stream) {
  (void)in_sizes; (void)n_in; (void)out_size; (void)ws_size;
  const float* spike = (const float*)d_in[0];
  const float* extin = (const float*)d_in[1];
  const int*   lens  = (const int*)  d_in[2];
  const float* WiF   = (const float*)d_in[3];
  const float* WhF   = (const float*)d_in[4];
  const float* biF   = (const float*)d_in[5];
  const float* bhF   = (const float*)d_in[6];
  const float* WiB   = (const float*)d_in[7];
  const float* WhB   = (const float*)d_in[8];
  const float* biB   = (const float*)d_in[9];
  const float* bhB   = (const float*)d_in[10];
  float* out = (float*)d_out;
  char* ws = (char*)d_ws;
  unsigned* cnt = (unsigned*)(ws + CNT_OFF);
  char*     hx  = ws + HX_OFF;

  // zero counters + frag slots (slot 1 must be zero for the t=0 read; also
  // required between graph replays since the kernel leaves state behind)
  hipMemsetAsync(ws, 0, WS_ZERO_BYTES, stream);
  bigru2<<<dim3(128), dim3(WGS), 0, stream>>>(
      spike, extin, lens, WiF, WhF, biF, bhF, WiB, WhB, biB, bhB, out, cnt, hx);
}